// Round 1
// baseline (1131.351 us; speedup 1.0000x reference)
//
#include <hip/hip_runtime.h>

#define IN_DIM  256
#define OUT_DIM 128
#define ALPHA   0.1f
#define EPS     9e-15f

// ---------------- GEMM: h = x @ W  (f32 vector ALU; no fp32 MFMA on CDNA4) ---
// Block: 256 threads, computes 16 rows x 128 cols. Each thread: 4 rows x 2 cols.
__global__ __launch_bounds__(256) void gemm_xw(const float* __restrict__ x,
                                               const float* __restrict__ W,
                                               float* __restrict__ h) {
  __shared__ float xs[16 * IN_DIM];
  const int tid = threadIdx.x;
  const int block_row = blockIdx.x * 16;

  // Stage 16 rows of x (16x256 f32 = 16 KB) into LDS, float4-coalesced.
  const float4* xg = (const float4*)(x + (size_t)block_row * IN_DIM);
  float4* xs4 = (float4*)xs;
#pragma unroll
  for (int i = 0; i < 4; i++) xs4[tid + i * 256] = xg[tid + i * 256];
  __syncthreads();

  const int col = tid & 63;        // lanes 0..63 -> cols col and col+64
  const int rg  = tid >> 6;        // 4 row groups of 4 rows

  float acc[4][2] = {};
  for (int k = 0; k < IN_DIM; k += 4) {
    float4 xv[4];
#pragma unroll
    for (int r = 0; r < 4; r++)
      xv[r] = *(const float4*)&xs[(rg * 4 + r) * IN_DIM + k];
#pragma unroll
    for (int i = 0; i < 4; i++) {
      float wa = W[(k + i) * OUT_DIM + col];
      float wb = W[(k + i) * OUT_DIM + col + 64];
#pragma unroll
      for (int r = 0; r < 4; r++) {
        float xr = (&xv[r].x)[i];
        acc[r][0] = fmaf(xr, wa, acc[r][0]);
        acc[r][1] = fmaf(xr, wb, acc[r][1]);
      }
    }
  }
#pragma unroll
  for (int r = 0; r < 4; r++) {
    size_t row = (size_t)block_row + rg * 4 + r;
    h[row * OUT_DIM + col]      = acc[r][0];
    h[row * OUT_DIM + col + 64] = acc[r][1];
  }
}

// ---------------- scores: score_l = h @ a_l, score_r = h @ a_r ---------------
// One wave per node; lane handles cols {lane, lane+64}; shfl butterfly reduce.
__global__ __launch_bounds__(256) void scores_k(const float* __restrict__ h,
                                                const float* __restrict__ attn,
                                                float* __restrict__ score_l,
                                                float* __restrict__ score_r, int N) {
  int gwave = (blockIdx.x * blockDim.x + threadIdx.x) >> 6;
  int lane  = threadIdx.x & 63;
  if (gwave >= N) return;
  const float* hr = h + (size_t)gwave * OUT_DIM;
  float h0 = hr[lane], h1 = hr[lane + 64];
  float pl = h0 * attn[lane]       + h1 * attn[lane + 64];
  float pr = h0 * attn[128 + lane] + h1 * attn[192 + lane];
#pragma unroll
  for (int off = 32; off; off >>= 1) {
    pl += __shfl_down(pl, off);
    pr += __shfl_down(pr, off);
  }
  if (lane == 0) { score_l[gwave] = pl; score_r[gwave] = pr; }
}

// ---------------- CSR build: histogram by src ------------------------------
__global__ __launch_bounds__(256) void hist_k(const int* __restrict__ src,
                                              int* __restrict__ counts, int E) {
  int i = blockIdx.x * blockDim.x + threadIdx.x;
  if (i < E) atomicAdd(&counts[src[i]], 1);
}

// ---------------- exclusive scan of counts -> offsets, cursor --------------
// Single block of 1024 threads; each owns a contiguous chunk.
__global__ __launch_bounds__(1024) void scan_k(const int* __restrict__ counts,
                                               int* __restrict__ offsets,
                                               int* __restrict__ cursor, int N) {
  __shared__ int partial[1024];
  const int tid = threadIdx.x;
  const int chunk = (N + 1023) / 1024;
  const int start = tid * chunk;
  const int end   = min(start + chunk, N);
  int s = 0;
  for (int i = start; i < end; i++) s += counts[i];
  partial[tid] = s;
  __syncthreads();
  // Hillis-Steele inclusive scan over the 1024 partials
  for (int offd = 1; offd < 1024; offd <<= 1) {
    int v = (tid >= offd) ? partial[tid - offd] : 0;
    __syncthreads();
    partial[tid] += v;
    __syncthreads();
  }
  int run = (tid == 0) ? 0 : partial[tid - 1];
  for (int i = start; i < end; i++) {
    offsets[i] = run;
    cursor[i]  = run;
    run += counts[i];
  }
  if (start < N && end == N) offsets[N] = run;  // total = E
}

// ---------------- scatter edges into CSR order, computing e ----------------
__global__ __launch_bounds__(256) void scatter_k(const int* __restrict__ src,
                                                 const int* __restrict__ dst,
                                                 const float* __restrict__ score_l,
                                                 const float* __restrict__ score_r,
                                                 int* __restrict__ cursor,
                                                 int* __restrict__ dst_sorted,
                                                 float* __restrict__ e_sorted, int E) {
  int i = blockIdx.x * blockDim.x + threadIdx.x;
  if (i >= E) return;
  int s = src[i], d = dst[i];
  float v = score_l[s] + score_r[d];
  float a = v > 0.0f ? v : ALPHA * v;
  // NOTE: global max subtraction cancels in S/(R+EPS) (EPS=9e-15 negligible);
  // f32 range is safe (max score ~ +18 -> exp ~ 5e8).
  float e = expf(a);
  int pos = atomicAdd(&cursor[s], 1);
  dst_sorted[pos] = d;
  e_sorted[pos]   = e;
}

// ---------------- aggregate: one wave per node, 2 cols per lane ------------
__global__ __launch_bounds__(256) void aggregate_k(const int* __restrict__ offsets,
                                                   const int* __restrict__ dst_sorted,
                                                   const float* __restrict__ e_sorted,
                                                   const float* __restrict__ h,
                                                   float* __restrict__ out, int N) {
  int node = (blockIdx.x * blockDim.x + threadIdx.x) >> 6;
  int lane = threadIdx.x & 63;
  if (node >= N) return;
  int beg = offsets[node], end = offsets[node + 1];
  float acc0 = 0.0f, acc1 = 0.0f, esum = 0.0f;
  for (int j = beg; j < end; j++) {
    int d   = dst_sorted[j];      // wave-uniform
    float e = e_sorted[j];        // wave-uniform
    float2 hv = ((const float2*)(h + (size_t)d * OUT_DIM))[lane];  // 512B/wave
    acc0 = fmaf(e, hv.x, acc0);
    acc1 = fmaf(e, hv.y, acc1);
    esum += e;                    // every lane accumulates full rowsum
  }
  float inv = 1.0f / (esum + EPS);
  float o0 = acc0 * inv, o1 = acc1 * inv;
  o0 = o0 > 0.0f ? o0 : ALPHA * o0;
  o1 = o1 > 0.0f ? o1 : ALPHA * o1;
  ((float2*)(out + (size_t)node * OUT_DIM))[lane] = make_float2(o0, o1);
}

extern "C" void kernel_launch(void* const* d_in, const int* in_sizes, int n_in,
                              void* d_out, int out_size, void* d_ws, size_t ws_size,
                              hipStream_t stream) {
  const float* x    = (const float*)d_in[0];
  const int*   ei   = (const int*)d_in[1];
  const float* W    = (const float*)d_in[2];
  const float* attn = (const float*)d_in[3];
  const int N = in_sizes[0] / IN_DIM;
  const int E = in_sizes[1] / 2;
  const int* src = ei;
  const int* dst = ei + E;
  float* out = (float*)d_out;

  char* ws = (char*)d_ws;
  size_t off = 0;
  auto alloc = [&](size_t bytes) -> void* {
    void* p = ws + off;
    off += (bytes + 255) & ~(size_t)255;
    return p;
  };
  float* h          = (float*)alloc((size_t)N * OUT_DIM * 4);
  float* score_l    = (float*)alloc((size_t)N * 4);
  float* score_r    = (float*)alloc((size_t)N * 4);
  int*   counts     = (int*)  alloc((size_t)N * 4);
  int*   offsets    = (int*)  alloc(((size_t)N + 1) * 4);
  int*   cursor     = (int*)  alloc((size_t)N * 4);
  int*   dst_sorted = (int*)  alloc((size_t)E * 4);
  float* e_sorted   = (float*)alloc((size_t)E * 4);

  hipMemsetAsync(counts, 0, (size_t)N * 4, stream);

  gemm_xw<<<N / 16, 256, 0, stream>>>(x, W, h);
  scores_k<<<(N + 3) / 4, 256, 0, stream>>>(h, attn, score_l, score_r, N);
  hist_k<<<(E + 255) / 256, 256, 0, stream>>>(src, counts, E);
  scan_k<<<1, 1024, 0, stream>>>(counts, offsets, cursor, N);
  scatter_k<<<(E + 255) / 256, 256, 0, stream>>>(src, dst, score_l, score_r,
                                                 cursor, dst_sorted, e_sorted, E);
  aggregate_k<<<(N + 3) / 4, 256, 0, stream>>>(offsets, dst_sorted, e_sorted, h, out, N);
}

// Round 2
// 950.987 us; speedup vs baseline: 1.1897x; 1.1897x over previous
//
#include <hip/hip_runtime.h>

#define IN_DIM  256
#define OUT_DIM 128
#define ALPHA   0.1f
#define EPS     9e-15f

static __device__ __forceinline__ unsigned bf16_rne(float f) {
  unsigned u = __float_as_uint(f);
  return (u + 0x7fffu + ((u >> 16) & 1u)) >> 16;
}

// ---- GEMM + scores fused: hb(bf16 packed) = x@W ; score_l/r = h@a_l/r ------
// Block: 256 threads = 4 waves; wave w computes rows (blk*16 + w*4 .. +3).
// Lane handles cols {2*lane, 2*lane+1}.
__global__ __launch_bounds__(256) void gemm_fused(const float* __restrict__ x,
                                                  const float* __restrict__ W,
                                                  const float* __restrict__ attn,
                                                  unsigned* __restrict__ hb,
                                                  float* __restrict__ score_l,
                                                  float* __restrict__ score_r) {
  __shared__ float xs[16 * IN_DIM];
  const int tid = threadIdx.x;
  const int block_row = blockIdx.x * 16;

  const float4* xg = (const float4*)(x + (size_t)block_row * IN_DIM);
  float4* xs4 = (float4*)xs;
#pragma unroll
  for (int i = 0; i < 4; i++) xs4[tid + i * 256] = xg[tid + i * 256];
  __syncthreads();

  const int lane = tid & 63;
  const int wv   = tid >> 6;

  float acc[4][2] = {};
  for (int k = 0; k < IN_DIM; k += 4) {
    float4 xv[4];
#pragma unroll
    for (int r = 0; r < 4; r++)
      xv[r] = *(const float4*)&xs[(wv * 4 + r) * IN_DIM + k];
#pragma unroll
    for (int i = 0; i < 4; i++) {
      float2 w2 = *(const float2*)&W[(size_t)(k + i) * OUT_DIM + 2 * lane];
#pragma unroll
      for (int r = 0; r < 4; r++) {
        float xr = (&xv[r].x)[i];
        acc[r][0] = fmaf(xr, w2.x, acc[r][0]);
        acc[r][1] = fmaf(xr, w2.y, acc[r][1]);
      }
    }
  }

  const float2 al = *(const float2*)&attn[2 * lane];
  const float2 ar = *(const float2*)&attn[OUT_DIM + 2 * lane];
#pragma unroll
  for (int r = 0; r < 4; r++) {
    const int row = block_row + wv * 4 + r;
    hb[(size_t)row * 64 + lane] = bf16_rne(acc[r][0]) | (bf16_rne(acc[r][1]) << 16);
    float pl = acc[r][0] * al.x + acc[r][1] * al.y;
    float pr = acc[r][0] * ar.x + acc[r][1] * ar.y;
#pragma unroll
    for (int off = 32; off; off >>= 1) {
      pl += __shfl_down(pl, off);
      pr += __shfl_down(pr, off);
    }
    if (lane == 0) { score_l[row] = pl; score_r[row] = pr; }
  }
}

// ---------------- CSR build: histogram by src ------------------------------
__global__ __launch_bounds__(256) void hist_k(const int* __restrict__ src,
                                              int* __restrict__ counts, int E) {
  int i = blockIdx.x * blockDim.x + threadIdx.x;
  if (i < E) atomicAdd(&counts[src[i]], 1);
}

// ---------------- exclusive scan of counts -> offsets, cursor --------------
__global__ __launch_bounds__(1024) void scan_k(const int* __restrict__ counts,
                                               int* __restrict__ offsets,
                                               int* __restrict__ cursor, int N) {
  __shared__ int partial[1024];
  const int tid = threadIdx.x;
  const int chunk = (N + 1023) / 1024;
  const int start = tid * chunk;
  const int end   = min(start + chunk, N);
  int s = 0;
  for (int i = start; i < end; i++) s += counts[i];
  partial[tid] = s;
  __syncthreads();
  for (int offd = 1; offd < 1024; offd <<= 1) {
    int v = (tid >= offd) ? partial[tid - offd] : 0;
    __syncthreads();
    partial[tid] += v;
    __syncthreads();
  }
  int run = (tid == 0) ? 0 : partial[tid - 1];
  for (int i = start; i < end; i++) {
    offsets[i] = run;
    cursor[i]  = run;
    run += counts[i];
  }
  if (start < N && end == N) offsets[N] = run;
}

// -------- scatter edges into CSR order as packed (dst, e) int2 -------------
__global__ __launch_bounds__(256) void scatter_k(const int* __restrict__ src,
                                                 const int* __restrict__ dst,
                                                 const float* __restrict__ score_l,
                                                 const float* __restrict__ score_r,
                                                 int* __restrict__ cursor,
                                                 int2* __restrict__ es, int E) {
  int i = blockIdx.x * blockDim.x + threadIdx.x;
  if (i >= E) return;
  int s = src[i], d = dst[i];
  float v = score_l[s] + score_r[d];
  float a = v > 0.0f ? v : ALPHA * v;
  // global max subtraction cancels in S/(R+EPS); f32 range safe (exp <= ~5e8)
  float e = expf(a);
  int pos = atomicAdd(&cursor[s], 1);
  es[pos] = make_int2(d, __float_as_int(e));
}

// ---- aggregate: one wave per node; 16 lanes/edge (8 bf16 cols each);
// ---- 4 edges concurrent per iteration, unrolled x2 -> 8 gathers in flight.
__global__ __launch_bounds__(256) void aggregate_k(const int* __restrict__ offsets,
                                                   const int2* __restrict__ es,
                                                   const unsigned* __restrict__ hb,
                                                   float* __restrict__ out, int N) {
  const int node = (blockIdx.x * blockDim.x + threadIdx.x) >> 6;
  const int lane = threadIdx.x & 63;
  if (node >= N) return;
  const int q  = lane >> 4;   // quarter: which of 4 concurrent edges
  const int sl = lane & 15;   // 8 cols: sl*8 .. sl*8+7

  const int beg = offsets[node], end = offsets[node + 1];
  float acc[8] = {};
  float esum = 0.0f;

  int j = beg;
  for (; j + 8 <= end; j += 8) {
    int2 ea = es[j + q];
    int2 eb = es[j + 4 + q];
    uint4 ha = *(const uint4*)(hb + (size_t)ea.x * 64 + sl * 4);
    uint4 hc = *(const uint4*)(hb + (size_t)eb.x * 64 + sl * 4);
    float e0 = __int_as_float(ea.y);
    float e1 = __int_as_float(eb.y);
    const unsigned* pa = &ha.x;
    const unsigned* pb = &hc.x;
#pragma unroll
    for (int i = 0; i < 4; i++) {
      unsigned ua = pa[i], ub = pb[i];
      acc[2*i]   = fmaf(e0, __uint_as_float(ua << 16), acc[2*i]);
      acc[2*i+1] = fmaf(e0, __uint_as_float(ua & 0xffff0000u), acc[2*i+1]);
      acc[2*i]   = fmaf(e1, __uint_as_float(ub << 16), acc[2*i]);
      acc[2*i+1] = fmaf(e1, __uint_as_float(ub & 0xffff0000u), acc[2*i+1]);
    }
    esum += e0 + e1;
  }
  for (; j < end; j += 4) {
    if (j + q < end) {
      int2 ea = es[j + q];
      uint4 ha = *(const uint4*)(hb + (size_t)ea.x * 64 + sl * 4);
      float e0 = __int_as_float(ea.y);
      const unsigned* pa = &ha.x;
#pragma unroll
      for (int i = 0; i < 4; i++) {
        unsigned ua = pa[i];
        acc[2*i]   = fmaf(e0, __uint_as_float(ua << 16), acc[2*i]);
        acc[2*i+1] = fmaf(e0, __uint_as_float(ua & 0xffff0000u), acc[2*i+1]);
      }
      esum += e0;
    }
  }

  // combine the 4 quarters (xor-16 then xor-32), esum too
#pragma unroll
  for (int m = 16; m <= 32; m <<= 1) {
#pragma unroll
    for (int c = 0; c < 8; c++) acc[c] += __shfl_xor(acc[c], m);
    esum += __shfl_xor(esum, m);
  }

  if (q == 0) {
    float inv = 1.0f / (esum + EPS);
    float o[8];
#pragma unroll
    for (int c = 0; c < 8; c++) {
      float v = acc[c] * inv;
      o[c] = v > 0.0f ? v : ALPHA * v;
    }
    float* op = out + (size_t)node * OUT_DIM + sl * 8;
    *(float4*)(op)     = make_float4(o[0], o[1], o[2], o[3]);
    *(float4*)(op + 4) = make_float4(o[4], o[5], o[6], o[7]);
  }
}

extern "C" void kernel_launch(void* const* d_in, const int* in_sizes, int n_in,
                              void* d_out, int out_size, void* d_ws, size_t ws_size,
                              hipStream_t stream) {
  const float* x    = (const float*)d_in[0];
  const int*   ei   = (const int*)d_in[1];
  const float* W    = (const float*)d_in[2];
  const float* attn = (const float*)d_in[3];
  const int N = in_sizes[0] / IN_DIM;
  const int E = in_sizes[1] / 2;
  const int* src = ei;
  const int* dst = ei + E;
  float* out = (float*)d_out;

  char* ws = (char*)d_ws;
  size_t off = 0;
  auto alloc = [&](size_t bytes) -> void* {
    void* p = ws + off;
    off += (bytes + 255) & ~(size_t)255;
    return p;
  };
  unsigned* hb      = (unsigned*)alloc((size_t)N * 64 * 4);   // bf16-packed h
  float* score_l    = (float*)alloc((size_t)N * 4);
  float* score_r    = (float*)alloc((size_t)N * 4);
  int*   counts     = (int*)  alloc((size_t)N * 4);
  int*   offsets    = (int*)  alloc(((size_t)N + 1) * 4);
  int*   cursor     = (int*)  alloc((size_t)N * 4);
  int2*  es         = (int2*) alloc((size_t)E * 8);

  hipMemsetAsync(counts, 0, (size_t)N * 4, stream);

  gemm_fused<<<N / 16, 256, 0, stream>>>(x, W, attn, hb, score_l, score_r);
  hist_k<<<(E + 255) / 256, 256, 0, stream>>>(src, counts, E);
  scan_k<<<1, 1024, 0, stream>>>(counts, offsets, cursor, N);
  scatter_k<<<(E + 255) / 256, 256, 0, stream>>>(src, dst, score_l, score_r,
                                                 cursor, es, E);
  aggregate_k<<<(N + 3) / 4, 256, 0, stream>>>(offsets, es, hb, out, N);
}

// Round 3
// 814.976 us; speedup vs baseline: 1.3882x; 1.1669x over previous
//
#include <hip/hip_runtime.h>

#define IN_DIM  256
#define OUT_DIM 128
#define ALPHA   0.1f
#define EPS     9e-15f

typedef __attribute__((ext_vector_type(4))) float f32x4;
typedef __attribute__((ext_vector_type(8))) short bf16x8;

static __device__ __forceinline__ unsigned bf16_rne(float f) {
  unsigned u = __float_as_uint(f);
  return (u + 0x7fffu + ((u >> 16) & 1u)) >> 16;
}
static __device__ __forceinline__ unsigned pk2(float lo, float hi) {
  return bf16_rne(lo) | (bf16_rne(hi) << 16);
}
static __device__ __forceinline__ void load_lds_16(const void* g, void* l) {
  __builtin_amdgcn_global_load_lds(
      (const __attribute__((address_space(1))) void*)g,
      (__attribute__((address_space(3))) void*)l, 16, 0, 0);
}

// ---- W pre-pack into MFMA B-fragment order (bf16) -------------------------
// Wf[(ct*8+kk)*64 + l] (uint4 = 8 bf16): j=0..7 -> W[kk*32+(l>>4)*8+j][ct*16+(l&15)]
__global__ __launch_bounds__(256) void wconv_k(const float* __restrict__ W,
                                               uint4* __restrict__ Wf) {
  int t = blockIdx.x * 256 + threadIdx.x;   // 0..4095
  int ct = t >> 9, kk = (t >> 6) & 7, l = t & 63;
  int kbase = kk * 32 + (l >> 4) * 8;
  int col = ct * 16 + (l & 15);
  float v[8];
#pragma unroll
  for (int j = 0; j < 8; j++) v[j] = W[(size_t)(kbase + j) * OUT_DIM + col];
  uint4 o;
  o.x = pk2(v[0], v[1]); o.y = pk2(v[2], v[3]);
  o.z = pk2(v[4], v[5]); o.w = pk2(v[6], v[7]);
  Wf[t] = o;
}

// ---- MFMA GEMM + scores + bf16 pack, 64 rows x 128 cols per block ---------
__global__ __launch_bounds__(256) void gemm_mfma(const float* __restrict__ x,
                                                 const uint4* __restrict__ Wf,
                                                 const float* __restrict__ attn,
                                                 unsigned* __restrict__ hb,
                                                 float* __restrict__ score_l,
                                                 float* __restrict__ score_r,
                                                 int N) {
  __shared__ float xs[64 * IN_DIM];   // 64 KB; 16B units swizzled: LDS[row][u]=x[row][u^(row&15)]
  const int tid  = threadIdx.x;
  const int lane = tid & 63;
  const int w    = tid >> 6;
  const int row0 = blockIdx.x * 64;

  // Stage x tile via async global->LDS, pre-swizzling the SOURCE address.
  const char* xb = (const char*)x;
#pragma unroll
  for (int i = 0; i < 16; i++) {
    int u   = i * 256 + tid;        // linear 16B-unit in LDS
    int row = u >> 6, uir = u & 63;
    int srow = row0 + row; if (srow >= N) srow = N - 1;   // tail clamp
    const void* src = xb + (size_t)srow * 1024 + (size_t)((uir ^ (row & 15)) * 16);
    load_lds_16(src, (char*)xs + (size_t)(i * 256 + w * 64) * 16);
  }
  __syncthreads();

  const int rquad = lane >> 4;    // 0..3
  const int a15   = lane & 15;
  const int rloc  = w * 16 + a15; // this lane's A row (local)

  // A-fragments for all 8 K-steps, converted f32->bf16 on read.
  bf16x8 afrag[8];
#pragma unroll
  for (int kk = 0; kk < 8; kk++) {
    int u0 = kk * 8 + rquad * 2;
    f32x4 p0 = *(const f32x4*)&xs[rloc * IN_DIM + ((u0 ^ a15) * 4)];
    f32x4 p1 = *(const f32x4*)&xs[rloc * IN_DIM + (((u0 + 1) ^ a15) * 4)];
    union { unsigned u[4]; bf16x8 v; } cvt;
    cvt.u[0] = pk2(p0.x, p0.y); cvt.u[1] = pk2(p0.z, p0.w);
    cvt.u[2] = pk2(p1.x, p1.y); cvt.u[3] = pk2(p1.z, p1.w);
    afrag[kk] = cvt.v;
  }

  const float* al = attn;
  const float* ar = attn + OUT_DIM;
  float pl[4] = {}, pr[4] = {};
  const int growbase = row0 + w * 16;

  for (int ct = 0; ct < 8; ct++) {
    f32x4 acc = {0.f, 0.f, 0.f, 0.f};
#pragma unroll
    for (int kk = 0; kk < 8; kk++) {
      bf16x8 bfrag = *(const bf16x8*)&Wf[(ct * 8 + kk) * 64 + lane];
      acc = __builtin_amdgcn_mfma_f32_16x16x32_bf16(afrag[kk], bfrag, acc, 0, 0, 0);
    }
    // C/D mapping: col = ct*16 + (lane&15), row = rquad*4 + reg
    const int col = ct * 16 + a15;
    const float aL = al[col], aR = ar[col];
#pragma unroll
    for (int r = 0; r < 4; r++) {
      float v = acc[r];
      pl[r] = fmaf(v, aL, pl[r]);
      pr[r] = fmaf(v, aR, pr[r]);
      float partner = __shfl_xor(v, 1);        // odd column's value
      int grow = growbase + rquad * 4 + r;
      if (((lane & 1) == 0) && grow < N)
        hb[(size_t)grow * 64 + (col >> 1)] = pk2(v, partner);
    }
  }

  // score reduce across the 16 lanes sharing a row-quad
#pragma unroll
  for (int m = 1; m <= 8; m <<= 1) {
#pragma unroll
    for (int r = 0; r < 4; r++) {
      pl[r] += __shfl_xor(pl[r], m);
      pr[r] += __shfl_xor(pr[r], m);
    }
  }
  if (a15 == 0) {
#pragma unroll
    for (int r = 0; r < 4; r++) {
      int grow = growbase + rquad * 4 + r;
      if (grow < N) { score_l[grow] = pl[r]; score_r[grow] = pr[r]; }
    }
  }
}

// ---------------- CSR build: histogram by src ------------------------------
__global__ __launch_bounds__(256) void hist_k(const int* __restrict__ src,
                                              int* __restrict__ counts, int E) {
  int i = blockIdx.x * blockDim.x + threadIdx.x;
  if (i < E) atomicAdd(&counts[src[i]], 1);
}

// ---------------- exclusive scan of counts -> offsets, cursor --------------
__global__ __launch_bounds__(1024) void scan_k(const int* __restrict__ counts,
                                               int* __restrict__ offsets,
                                               int* __restrict__ cursor, int N) {
  __shared__ int partial[1024];
  const int tid = threadIdx.x;
  const int chunk = (N + 1023) / 1024;
  const int start = tid * chunk;
  const int end   = min(start + chunk, N);
  int s = 0;
  for (int i = start; i < end; i++) s += counts[i];
  partial[tid] = s;
  __syncthreads();
  for (int offd = 1; offd < 1024; offd <<= 1) {
    int v = (tid >= offd) ? partial[tid - offd] : 0;
    __syncthreads();
    partial[tid] += v;
    __syncthreads();
  }
  int run = (tid == 0) ? 0 : partial[tid - 1];
  for (int i = start; i < end; i++) {
    offsets[i] = run;
    cursor[i]  = run;
    run += counts[i];
  }
  if (start < N && end == N) offsets[N] = run;
}

// -------- scatter edges into CSR order as packed (dst, e) int2 -------------
__global__ __launch_bounds__(256) void scatter_k(const int* __restrict__ src,
                                                 const int* __restrict__ dst,
                                                 const float* __restrict__ score_l,
                                                 const float* __restrict__ score_r,
                                                 int* __restrict__ cursor,
                                                 int2* __restrict__ es, int E) {
  int i = blockIdx.x * blockDim.x + threadIdx.x;
  if (i >= E) return;
  int s = src[i], d = dst[i];
  float v = score_l[s] + score_r[d];
  float a = v > 0.0f ? v : ALPHA * v;
  // global max subtraction cancels in S/(R+EPS); f32 range safe (exp <= ~5e8)
  float e = expf(a);
  int pos = atomicAdd(&cursor[s], 1);
  es[pos] = make_int2(d, __float_as_int(e));
}

// ---- aggregate: one wave per node; 16 lanes/edge (8 bf16 cols each);
// ---- 4 edges concurrent per iteration, unrolled x2 -> 8 gathers in flight.
__global__ __launch_bounds__(256) void aggregate_k(const int* __restrict__ offsets,
                                                   const int2* __restrict__ es,
                                                   const unsigned* __restrict__ hb,
                                                   float* __restrict__ out, int N) {
  const int node = (blockIdx.x * blockDim.x + threadIdx.x) >> 6;
  const int lane = threadIdx.x & 63;
  if (node >= N) return;
  const int q  = lane >> 4;
  const int sl = lane & 15;

  const int beg = offsets[node], end = offsets[node + 1];
  float acc[8] = {};
  float esum = 0.0f;

  int j = beg;
  for (; j + 8 <= end; j += 8) {
    int2 ea = es[j + q];
    int2 eb = es[j + 4 + q];
    uint4 ha = *(const uint4*)(hb + (size_t)ea.x * 64 + sl * 4);
    uint4 hc = *(const uint4*)(hb + (size_t)eb.x * 64 + sl * 4);
    float e0 = __int_as_float(ea.y);
    float e1 = __int_as_float(eb.y);
    const unsigned* pa = &ha.x;
    const unsigned* pb = &hc.x;
#pragma unroll
    for (int i = 0; i < 4; i++) {
      unsigned ua = pa[i], ub = pb[i];
      acc[2*i]   = fmaf(e0, __uint_as_float(ua << 16), acc[2*i]);
      acc[2*i+1] = fmaf(e0, __uint_as_float(ua & 0xffff0000u), acc[2*i+1]);
      acc[2*i]   = fmaf(e1, __uint_as_float(ub << 16), acc[2*i]);
      acc[2*i+1] = fmaf(e1, __uint_as_float(ub & 0xffff0000u), acc[2*i+1]);
    }
    esum += e0 + e1;
  }
  for (; j < end; j += 4) {
    if (j + q < end) {
      int2 ea = es[j + q];
      uint4 ha = *(const uint4*)(hb + (size_t)ea.x * 64 + sl * 4);
      float e0 = __int_as_float(ea.y);
      const unsigned* pa = &ha.x;
#pragma unroll
      for (int i = 0; i < 4; i++) {
        unsigned ua = pa[i];
        acc[2*i]   = fmaf(e0, __uint_as_float(ua << 16), acc[2*i]);
        acc[2*i+1] = fmaf(e0, __uint_as_float(ua & 0xffff0000u), acc[2*i+1]);
      }
      esum += e0;
    }
  }

#pragma unroll
  for (int m = 16; m <= 32; m <<= 1) {
#pragma unroll
    for (int c = 0; c < 8; c++) acc[c] += __shfl_xor(acc[c], m);
    esum += __shfl_xor(esum, m);
  }

  if (q == 0) {
    float inv = 1.0f / (esum + EPS);
    float o[8];
#pragma unroll
    for (int c = 0; c < 8; c++) {
      float v = acc[c] * inv;
      o[c] = v > 0.0f ? v : ALPHA * v;
    }
    float* op = out + (size_t)node * OUT_DIM + sl * 8;
    *(float4*)(op)     = make_float4(o[0], o[1], o[2], o[3]);
    *(float4*)(op + 4) = make_float4(o[4], o[5], o[6], o[7]);
  }
}

extern "C" void kernel_launch(void* const* d_in, const int* in_sizes, int n_in,
                              void* d_out, int out_size, void* d_ws, size_t ws_size,
                              hipStream_t stream) {
  const float* x    = (const float*)d_in[0];
  const int*   ei   = (const int*)d_in[1];
  const float* W    = (const float*)d_in[2];
  const float* attn = (const float*)d_in[3];
  const int N = in_sizes[0] / IN_DIM;
  const int E = in_sizes[1] / 2;
  const int* src = ei;
  const int* dst = ei + E;
  float* out = (float*)d_out;

  char* ws = (char*)d_ws;
  size_t off = 0;
  auto alloc = [&](size_t bytes) -> void* {
    void* p = ws + off;
    off += (bytes + 255) & ~(size_t)255;
    return p;
  };
  unsigned* hb      = (unsigned*)alloc((size_t)N * 64 * 4);   // bf16-packed h
  float* score_l    = (float*)alloc((size_t)N * 4);
  float* score_r    = (float*)alloc((size_t)N * 4);
  int*   counts     = (int*)  alloc((size_t)N * 4);
  int*   offsets    = (int*)  alloc(((size_t)N + 1) * 4);
  int*   cursor     = (int*)  alloc((size_t)N * 4);
  int2*  es         = (int2*) alloc((size_t)E * 8);
  uint4* Wf         = (uint4*)alloc((size_t)4096 * 16);       // fragment-packed W

  hipMemsetAsync(counts, 0, (size_t)N * 4, stream);

  wconv_k<<<16, 256, 0, stream>>>(W, Wf);
  gemm_mfma<<<(N + 63) / 64, 256, 0, stream>>>(x, Wf, attn, hb, score_l, score_r, N);
  hist_k<<<(E + 255) / 256, 256, 0, stream>>>(src, counts, E);
  scan_k<<<1, 1024, 0, stream>>>(counts, offsets, cursor, N);
  scatter_k<<<(E + 255) / 256, 256, 0, stream>>>(src, dst, score_l, score_r,
                                                 cursor, es, E);
  aggregate_k<<<(N + 3) / 4, 256, 0, stream>>>(offsets, es, hb, out, N);
}

// Round 4
// 602.642 us; speedup vs baseline: 1.8773x; 1.3523x over previous
//
#include <hip/hip_runtime.h>

#define IN_DIM  256
#define OUT_DIM 128
#define ALPHA   0.1f
#define EPS     9e-15f

typedef __attribute__((ext_vector_type(4))) float f32x4;
typedef __attribute__((ext_vector_type(8))) short bf16x8;

static __device__ __forceinline__ unsigned bf16_rne(float f) {
  unsigned u = __float_as_uint(f);
  return (u + 0x7fffu + ((u >> 16) & 1u)) >> 16;
}
static __device__ __forceinline__ unsigned pk2(float lo, float hi) {
  return bf16_rne(lo) | (bf16_rne(hi) << 16);
}
static __device__ __forceinline__ void load_lds_16(const void* g, void* l) {
  __builtin_amdgcn_global_load_lds(
      (const __attribute__((address_space(1))) void*)g,
      (__attribute__((address_space(3))) void*)l, 16, 0, 0);
}

// ---- W pre-pack into MFMA B-fragment order (bf16) -------------------------
__global__ __launch_bounds__(256) void wconv_k(const float* __restrict__ W,
                                               uint4* __restrict__ Wf) {
  int t = blockIdx.x * 256 + threadIdx.x;   // 0..4095
  int ct = t >> 9, kk = (t >> 6) & 7, l = t & 63;
  int kbase = kk * 32 + (l >> 4) * 8;
  int col = ct * 16 + (l & 15);
  float v[8];
#pragma unroll
  for (int j = 0; j < 8; j++) v[j] = W[(size_t)(kbase + j) * OUT_DIM + col];
  uint4 o;
  o.x = pk2(v[0], v[1]); o.y = pk2(v[2], v[3]);
  o.z = pk2(v[4], v[5]); o.w = pk2(v[6], v[7]);
  Wf[t] = o;
}

// ---- MFMA GEMM + scores + bf16 pack, 64 rows x 128 cols per block ---------
__global__ __launch_bounds__(256) void gemm_mfma(const float* __restrict__ x,
                                                 const uint4* __restrict__ Wf,
                                                 const float* __restrict__ attn,
                                                 unsigned* __restrict__ hb,
                                                 float* __restrict__ score_l,
                                                 float* __restrict__ score_r,
                                                 int N) {
  __shared__ float xs[64 * IN_DIM];   // 64 KB; LDS[row][u]=x[row][u^(row&15)] (16B units)
  const int tid  = threadIdx.x;
  const int lane = tid & 63;
  const int w    = tid >> 6;
  const int row0 = blockIdx.x * 64;

  const char* xb = (const char*)x;
#pragma unroll
  for (int i = 0; i < 16; i++) {
    int u   = i * 256 + tid;
    int row = u >> 6, uir = u & 63;
    int srow = row0 + row; if (srow >= N) srow = N - 1;
    const void* src = xb + (size_t)srow * 1024 + (size_t)((uir ^ (row & 15)) * 16);
    load_lds_16(src, (char*)xs + (size_t)(i * 256 + w * 64) * 16);
  }
  __syncthreads();

  const int rquad = lane >> 4;
  const int a15   = lane & 15;
  const int rloc  = w * 16 + a15;

  bf16x8 afrag[8];
#pragma unroll
  for (int kk = 0; kk < 8; kk++) {
    int u0 = kk * 8 + rquad * 2;
    f32x4 p0 = *(const f32x4*)&xs[rloc * IN_DIM + ((u0 ^ a15) * 4)];
    f32x4 p1 = *(const f32x4*)&xs[rloc * IN_DIM + (((u0 + 1) ^ a15) * 4)];
    union { unsigned u[4]; bf16x8 v; } cvt;
    cvt.u[0] = pk2(p0.x, p0.y); cvt.u[1] = pk2(p0.z, p0.w);
    cvt.u[2] = pk2(p1.x, p1.y); cvt.u[3] = pk2(p1.z, p1.w);
    afrag[kk] = cvt.v;
  }

  const float* al = attn;
  const float* ar = attn + OUT_DIM;
  float pl[4] = {}, pr[4] = {};
  const int growbase = row0 + w * 16;

  for (int ct = 0; ct < 8; ct++) {
    f32x4 acc = {0.f, 0.f, 0.f, 0.f};
#pragma unroll
    for (int kk = 0; kk < 8; kk++) {
      bf16x8 bfrag = *(const bf16x8*)&Wf[(ct * 8 + kk) * 64 + lane];
      acc = __builtin_amdgcn_mfma_f32_16x16x32_bf16(afrag[kk], bfrag, acc, 0, 0, 0);
    }
    const int col = ct * 16 + a15;
    const float aL = al[col], aR = ar[col];
#pragma unroll
    for (int r = 0; r < 4; r++) {
      float v = acc[r];
      pl[r] = fmaf(v, aL, pl[r]);
      pr[r] = fmaf(v, aR, pr[r]);
      float partner = __shfl_xor(v, 1);
      int grow = growbase + rquad * 4 + r;
      if (((lane & 1) == 0) && grow < N)
        hb[(size_t)grow * 64 + (col >> 1)] = pk2(v, partner);
    }
  }

#pragma unroll
  for (int m = 1; m <= 8; m <<= 1) {
#pragma unroll
    for (int r = 0; r < 4; r++) {
      pl[r] += __shfl_xor(pl[r], m);
      pr[r] += __shfl_xor(pr[r], m);
    }
  }
  if (a15 == 0) {
#pragma unroll
    for (int r = 0; r < 4; r++) {
      int grow = growbase + rquad * 4 + r;
      if (grow < N) { score_l[grow] = pl[r]; score_r[grow] = pr[r]; }
    }
  }
}

// ---------------- CSR build: histogram by src ------------------------------
__global__ __launch_bounds__(256) void hist_k(const int* __restrict__ src,
                                              int* __restrict__ counts, int E) {
  int i = blockIdx.x * blockDim.x + threadIdx.x;
  if (i < E) atomicAdd(&counts[src[i]], 1);
}

// ---------------- multi-block exclusive scan (3 phases) --------------------
// Phase 1: per-block sums (1024 counts per block = 256 threads x 4)
__global__ __launch_bounds__(256) void blocksum_k(const int* __restrict__ counts,
                                                  int* __restrict__ blockSums, int N) {
  __shared__ int sm[256];
  const int t = threadIdx.x;
  const int base = blockIdx.x * 1024 + t * 4;
  int s = 0;
#pragma unroll
  for (int i = 0; i < 4; i++) { int idx = base + i; if (idx < N) s += counts[idx]; }
  sm[t] = s;
  __syncthreads();
  for (int o = 128; o; o >>= 1) {
    if (t < o) sm[t] += sm[t + o];
    __syncthreads();
  }
  if (t == 0) blockSums[blockIdx.x] = sm[0];
}

// Phase 2: scan the (<=256) block sums; also writes offsets[N] = E
__global__ __launch_bounds__(256) void scanblocks_k(const int* __restrict__ blockSums,
                                                    int* __restrict__ blockOff,
                                                    int* __restrict__ totalOut, int NB) {
  __shared__ int sm[256];
  const int t = threadIdx.x;
  sm[t] = (t < NB) ? blockSums[t] : 0;
  __syncthreads();
  for (int o = 1; o < 256; o <<= 1) {
    int u = (t >= o) ? sm[t - o] : 0;
    __syncthreads();
    sm[t] += u;
    __syncthreads();
  }
  if (t < NB) blockOff[t] = t ? sm[t - 1] : 0;
  if (t == NB - 1) *totalOut = sm[t];
}

// Phase 3: per-block exclusive scan + global offset -> offsets, cursor
__global__ __launch_bounds__(256) void scanoffsets_k(const int* __restrict__ counts,
                                                     const int* __restrict__ blockOff,
                                                     int* __restrict__ offsets,
                                                     int* __restrict__ cursor, int N) {
  __shared__ int sm[256];
  const int t = threadIdx.x;
  const int base = blockIdx.x * 1024 + t * 4;
  int c[4]; int s = 0;
#pragma unroll
  for (int i = 0; i < 4; i++) { int idx = base + i; c[i] = (idx < N) ? counts[idx] : 0; s += c[i]; }
  sm[t] = s;
  __syncthreads();
  for (int o = 1; o < 256; o <<= 1) {
    int u = (t >= o) ? sm[t - o] : 0;
    __syncthreads();
    sm[t] += u;
    __syncthreads();
  }
  int run = blockOff[blockIdx.x] + (t ? sm[t - 1] : 0);
#pragma unroll
  for (int i = 0; i < 4; i++) {
    int idx = base + i;
    if (idx < N) { offsets[idx] = run; cursor[idx] = run; run += c[i]; }
  }
}

// -------- scatter edges into CSR order as packed (dst, e) int2 -------------
__global__ __launch_bounds__(256) void scatter_k(const int* __restrict__ src,
                                                 const int* __restrict__ dst,
                                                 const float* __restrict__ score_l,
                                                 const float* __restrict__ score_r,
                                                 int* __restrict__ cursor,
                                                 int2* __restrict__ es, int E) {
  int i = blockIdx.x * blockDim.x + threadIdx.x;
  if (i >= E) return;
  int s = src[i], d = dst[i];
  float v = score_l[s] + score_r[d];
  float a = v > 0.0f ? v : ALPHA * v;
  // global max subtraction cancels in S/(R+EPS); f32 range safe (exp <= ~5e8)
  float e = expf(a);
  int pos = atomicAdd(&cursor[s], 1);
  es[pos] = make_int2(d, __float_as_int(e));
}

// ---- aggregate: one wave per node; 16 lanes/edge (8 bf16 cols each) -------
__global__ __launch_bounds__(256) void aggregate_k(const int* __restrict__ offsets,
                                                   const int2* __restrict__ es,
                                                   const unsigned* __restrict__ hb,
                                                   float* __restrict__ out, int N) {
  const int node = (blockIdx.x * blockDim.x + threadIdx.x) >> 6;
  const int lane = threadIdx.x & 63;
  if (node >= N) return;
  const int q  = lane >> 4;
  const int sl = lane & 15;

  const int beg = offsets[node], end = offsets[node + 1];
  float acc[8] = {};
  float esum = 0.0f;

  int j = beg;
  for (; j + 8 <= end; j += 8) {
    int2 ea = es[j + q];
    int2 eb = es[j + 4 + q];
    uint4 ha = *(const uint4*)(hb + (size_t)ea.x * 64 + sl * 4);
    uint4 hc = *(const uint4*)(hb + (size_t)eb.x * 64 + sl * 4);
    float e0 = __int_as_float(ea.y);
    float e1 = __int_as_float(eb.y);
    const unsigned* pa = &ha.x;
    const unsigned* pb = &hc.x;
#pragma unroll
    for (int i = 0; i < 4; i++) {
      unsigned ua = pa[i], ub = pb[i];
      acc[2*i]   = fmaf(e0, __uint_as_float(ua << 16), acc[2*i]);
      acc[2*i+1] = fmaf(e0, __uint_as_float(ua & 0xffff0000u), acc[2*i+1]);
      acc[2*i]   = fmaf(e1, __uint_as_float(ub << 16), acc[2*i]);
      acc[2*i+1] = fmaf(e1, __uint_as_float(ub & 0xffff0000u), acc[2*i+1]);
    }
    esum += e0 + e1;
  }
  for (; j < end; j += 4) {
    if (j + q < end) {
      int2 ea = es[j + q];
      uint4 ha = *(const uint4*)(hb + (size_t)ea.x * 64 + sl * 4);
      float e0 = __int_as_float(ea.y);
      const unsigned* pa = &ha.x;
#pragma unroll
      for (int i = 0; i < 4; i++) {
        unsigned ua = pa[i];
        acc[2*i]   = fmaf(e0, __uint_as_float(ua << 16), acc[2*i]);
        acc[2*i+1] = fmaf(e0, __uint_as_float(ua & 0xffff0000u), acc[2*i+1]);
      }
      esum += e0;
    }
  }

#pragma unroll
  for (int m = 16; m <= 32; m <<= 1) {
#pragma unroll
    for (int c = 0; c < 8; c++) acc[c] += __shfl_xor(acc[c], m);
    esum += __shfl_xor(esum, m);
  }

  if (q == 0) {
    float inv = 1.0f / (esum + EPS);
    float o[8];
#pragma unroll
    for (int c = 0; c < 8; c++) {
      float v = acc[c] * inv;
      o[c] = v > 0.0f ? v : ALPHA * v;
    }
    float* op = out + (size_t)node * OUT_DIM + sl * 8;
    *(float4*)(op)     = make_float4(o[0], o[1], o[2], o[3]);
    *(float4*)(op + 4) = make_float4(o[4], o[5], o[6], o[7]);
  }
}

extern "C" void kernel_launch(void* const* d_in, const int* in_sizes, int n_in,
                              void* d_out, int out_size, void* d_ws, size_t ws_size,
                              hipStream_t stream) {
  const float* x    = (const float*)d_in[0];
  const int*   ei   = (const int*)d_in[1];
  const float* W    = (const float*)d_in[2];
  const float* attn = (const float*)d_in[3];
  const int N = in_sizes[0] / IN_DIM;
  const int E = in_sizes[1] / 2;
  const int* src = ei;
  const int* dst = ei + E;
  float* out = (float*)d_out;

  char* ws = (char*)d_ws;
  size_t off = 0;
  auto alloc = [&](size_t bytes) -> void* {
    void* p = ws + off;
    off += (bytes + 255) & ~(size_t)255;
    return p;
  };
  unsigned* hb      = (unsigned*)alloc((size_t)N * 64 * 4);   // bf16-packed h
  float* score_l    = (float*)alloc((size_t)N * 4);
  float* score_r    = (float*)alloc((size_t)N * 4);
  int*   counts     = (int*)  alloc((size_t)N * 4);
  int*   offsets    = (int*)  alloc(((size_t)N + 1) * 4);
  int*   cursor     = (int*)  alloc((size_t)N * 4);
  int2*  es         = (int2*) alloc((size_t)E * 8);
  uint4* Wf         = (uint4*)alloc((size_t)4096 * 16);       // fragment-packed W
  int*   blockSums  = (int*)  alloc(256 * 4);
  int*   blockOff   = (int*)  alloc(256 * 4);

  const int NB = (N + 1023) / 1024;   // 98 for N=100000 (must be <= 256)

  hipMemsetAsync(counts, 0, (size_t)N * 4, stream);

  wconv_k<<<16, 256, 0, stream>>>(W, Wf);
  gemm_mfma<<<(N + 63) / 64, 256, 0, stream>>>(x, Wf, attn, hb, score_l, score_r, N);
  hist_k<<<(E + 255) / 256, 256, 0, stream>>>(src, counts, E);
  blocksum_k<<<NB, 256, 0, stream>>>(counts, blockSums, N);
  scanblocks_k<<<1, 256, 0, stream>>>(blockSums, blockOff, &offsets[N], NB);
  scanoffsets_k<<<NB, 256, 0, stream>>>(counts, blockOff, offsets, cursor, N);
  scatter_k<<<(E + 255) / 256, 256, 0, stream>>>(src, dst, score_l, score_r,
                                                 cursor, es, E);
  aggregate_k<<<(N + 3) / 4, 256, 0, stream>>>(offsets, es, hb, out, N);
}